// Round 2
// baseline (406.270 us; speedup 1.0000x reference)
//
#include <hip/hip_runtime.h>

// Problem constants
#define BATCH 4
#define SEQQ  2048
#define SEQKV 2048
#define NH    4      // kv heads (effective q heads after group-sum)
#define HD    64
#define IND   1024

typedef __attribute__((ext_vector_type(8))) short short8;   // 8 x bf16 (raw bits)
typedef __attribute__((ext_vector_type(4))) float floatx4;  // MFMA accum

__device__ __forceinline__ short f2b(float f) {
    unsigned u; __builtin_memcpy(&u, &f, 4);
    u = (u + 0x7fffu + ((u >> 16) & 1u)) >> 16;   // RNE
    return (short)u;
}

__device__ __forceinline__ short8 cvt8(const float* p) {
    float4 a = *(const float4*)p;
    float4 b = *(const float4*)(p + 4);
    short8 r;
    r[0] = f2b(a.x); r[1] = f2b(a.y); r[2] = f2b(a.z); r[3] = f2b(a.w);
    r[4] = f2b(b.x); r[5] = f2b(b.y); r[6] = f2b(b.z); r[7] = f2b(b.w);
    return r;
}

// ---------------------------------------------------------------------------
// Weight prep (fp32 in, bf16 out): Wq group-sum + transpose to [N][K] (B^T).
//   Wq  [1024][16][64] f32 -> Wq_t  [256 n][1024 k] bf16, n=h*64+d, summed over g
//   Wk,Wv [1024][4][64] f32 -> Wkv_t [512 n][1024 k] bf16 (K: n<256, V: n>=256)
//   Wo  [256][1024] f32    -> Wo_t  [1024 n][256 k] bf16
// 1,048,576 threads exactly.
__global__ __launch_bounds__(256) void prep_weights(
    const float* __restrict__ Wq, const float* __restrict__ Wk,
    const float* __restrict__ Wv, const float* __restrict__ Wo,
    short* __restrict__ Wq_t, short* __restrict__ Wkv_t, short* __restrict__ Wo_t) {
    int idx = blockIdx.x * 256 + threadIdx.x;
    if (idx < 256 * 1024) {
        int n = idx >> 10, i = idx & 1023;
        int h = n >> 6, d = n & 63;
        float s = 0.f;
#pragma unroll
        for (int g = 0; g < 4; ++g) s += Wq[i * 1024 + (h * 4 + g) * 64 + d];
        Wq_t[idx] = f2b(s);
    } else if (idx < 768 * 1024) {
        int t = idx - 256 * 1024;
        int n = t >> 10, i = t & 1023;
        Wkv_t[t] = f2b((n < 256) ? Wk[i * 256 + n] : Wv[i * 256 + (n - 256)]);
    } else {
        int t = idx - 768 * 1024;
        int n = t >> 8, k = t & 255;
        Wo_t[t] = f2b(Wo[k * 1024 + n]);
    }
}

// ---------------------------------------------------------------------------
// GEMM: C[M][N](f32) = A[M][K] * Wt[N][K](bf16, B^T layout).
// A is fp32 (A_F32=true, converted in-register) or bf16 raw (A_F32=false).
// Block 256 = 4 waves; tile 64(M) x 64(N); wave = 16 rows x 64 cols.
template <bool A_F32>
__global__ __launch_bounds__(256) void gemm_bt(
    const void* __restrict__ Avoid, const short* __restrict__ Wt,
    float* __restrict__ Cout, int M, int N, int K) {
    const int m0 = blockIdx.x * 64, n0 = blockIdx.y * 64;
    const int w = threadIdx.x >> 6, lane = threadIdx.x & 63;
    const int ln = lane & 15, quad = lane >> 4;
    const long arow = (long)(m0 + w * 16 + ln) * K + quad * 8;
    floatx4 acc[4] = {{0,0,0,0},{0,0,0,0},{0,0,0,0},{0,0,0,0}};
    for (int k = 0; k < K; k += 32) {
        short8 a;
        if (A_F32) a = cvt8((const float*)Avoid + arow + k);
        else       a = *(const short8*)((const short*)Avoid + arow + k);
#pragma unroll
        for (int nt = 0; nt < 4; ++nt) {
            short8 b = *(const short8*)(Wt + (long)(n0 + nt * 16 + ln) * K + k + quad * 8);
            acc[nt] = __builtin_amdgcn_mfma_f32_16x16x32_bf16(a, b, acc[nt], 0, 0, 0);
        }
    }
    const int row0 = m0 + w * 16 + quad * 4;
#pragma unroll
    for (int nt = 0; nt < 4; ++nt) {
        int col = n0 + nt * 16 + ln;
#pragma unroll
        for (int r = 0; r < 4; ++r)
            Cout[(long)(row0 + r) * N + col] = acc[nt][r];
    }
}

// ---------------------------------------------------------------------------
// RoPE: d=64, a=2 axes, dpa=32, 16 freqs per axis.
// pair j in [0,32): axis=j>>4, f=j&15, angle = coord * 10000^(-f/16).
// Thread per pair. Qp [b*s][256] fp32 -> Qr [b][h][s][64] bf16.
__global__ __launch_bounds__(256) void rope_q_kernel(
    const float* __restrict__ Qp, const int* __restrict__ qc, short* __restrict__ Qr) {
    int idx = blockIdx.x * 256 + threadIdx.x;   // 1,048,576 total
    int j = idx & 31, h = (idx >> 5) & 3, s = (idx >> 7) & 2047, b = idx >> 18;
    int bs = b * 2048 + s;
    float2 x = *(const float2*)(Qp + (long)bs * 256 + h * 64 + 2 * j);
    float c = (float)qc[bs * 2 + (j >> 4)];
    float ang = c * __expf((float)(j & 15) * -0.5756462732485114f); // -ln(1e4)/16
    float sn, cs; __sincosf(ang, &sn, &cs);
    short2 o; o.x = f2b(x.x * cs - x.y * sn); o.y = f2b(x.x * sn + x.y * cs);
    *(short2*)(Qr + (long)((b * 4 + h) * 2048 + s) * 64 + 2 * j) = o;
}

// KVp [b*s][512] fp32 (K cols 0..255, V cols 256..511) -> Kr (RoPE), Vr (copy),
// both [b][h][s][64] bf16.
__global__ __launch_bounds__(256) void rope_kv_kernel(
    const float* __restrict__ KVp, const int* __restrict__ kvc,
    short* __restrict__ Kr, short* __restrict__ Vr) {
    int idx = blockIdx.x * 256 + threadIdx.x;
    int j = idx & 31, h = (idx >> 5) & 3, s = (idx >> 7) & 2047, b = idx >> 18;
    int bs = b * 2048 + s;
    const float* basep = KVp + (long)bs * 512 + h * 64 + 2 * j;
    float2 xk = *(const float2*)(basep);
    float2 xv = *(const float2*)(basep + 256);
    float c = (float)kvc[bs * 2 + (j >> 4)];
    float ang = c * __expf((float)(j & 15) * -0.5756462732485114f);
    float sn, cs; __sincosf(ang, &sn, &cs);
    long o = (long)((b * 4 + h) * 2048 + s) * 64 + 2 * j;
    short2 ok; ok.x = f2b(xk.x * cs - xk.y * sn); ok.y = f2b(xk.x * sn + xk.y * cs);
    *(short2*)(Kr + o) = ok;
    short2 ov; ov.x = f2b(xv.x); ov.y = f2b(xv.y);
    *(short2*)(Vr + o) = ov;
}

// ---------------------------------------------------------------------------
// Flash attention. Grid (SQ/64, B*NH), block 256 (4 waves x 16 q-rows).
// Qr/Kr/Vr [bh][s][64] bf16. Output Ob [b*s][256] bf16 (col = h*64+d).
// Per kv-tile(64): S = Q K^T (B-frags direct from global, contiguous-K),
// online softmax fp32, P -> LDS (stride 72: 2-way conflicts only, free),
// V staged transposed in LDS, O += P V.
__global__ __launch_bounds__(256) void attn_kernel(
    const short* __restrict__ Qr, const short* __restrict__ Kr,
    const short* __restrict__ Vr, short* __restrict__ Ob) {
    __shared__ __align__(16) short Vs[64][72];       // V-tile transposed [d][kv]
    __shared__ __align__(16) short Ps[4][16][72];    // per-wave P [q][kv]
    const int bh = blockIdx.y;
    const int q0 = blockIdx.x * 64;
    const int w = threadIdx.x >> 6, lane = threadIdx.x & 63;
    const int ln = lane & 15, quad = lane >> 4;
    const long base = (long)bh * SEQKV * HD;

    short8 qf[2];
    {
        const short* qp = Qr + base + (long)(q0 + w * 16 + ln) * HD + quad * 8;
        qf[0] = *(const short8*)(qp);
        qf[1] = *(const short8*)(qp + 32);
    }
    floatx4 o[4] = {{0,0,0,0},{0,0,0,0},{0,0,0,0},{0,0,0,0}};
    float mrow[4] = {-1e30f, -1e30f, -1e30f, -1e30f};
    float lrow[4] = {0.f, 0.f, 0.f, 0.f};

    for (int kt = 0; kt < SEQKV; kt += 64) {
        __syncthreads();   // prev iter's Vs/Ps reads done
        {   // stage V-tile transposed: thread -> 16 d-values of one kv row
            int kvr = threadIdx.x >> 2;
            int d0 = (threadIdx.x & 3) * 16;
            const short* vp = Vr + base + (long)(kt + kvr) * HD + d0;
            short8 v0 = *(const short8*)vp;
            short8 v1 = *(const short8*)(vp + 8);
#pragma unroll
            for (int jj = 0; jj < 8; ++jj) {
                Vs[d0 + jj][kvr] = v0[jj];
                Vs[d0 + 8 + jj][kvr] = v1[jj];
            }
        }
        __syncthreads();   // Vs visible

        floatx4 sf[4];
#pragma unroll
        for (int nt = 0; nt < 4; ++nt) {
            const short* kp = Kr + base + (long)(kt + nt * 16 + ln) * HD + quad * 8;
            short8 k0 = *(const short8*)kp;
            short8 k1 = *(const short8*)(kp + 32);
            floatx4 z = {0.f, 0.f, 0.f, 0.f};
            z = __builtin_amdgcn_mfma_f32_16x16x32_bf16(qf[0], k0, z, 0, 0, 0);
            z = __builtin_amdgcn_mfma_f32_16x16x32_bf16(qf[1], k1, z, 0, 0, 0);
            sf[nt] = z;
        }
        // online softmax, rows quad*4+r (replicated across the quad's 16 lanes)
#pragma unroll
        for (int r = 0; r < 4; ++r) {
            float mx = fmaxf(fmaxf(sf[0][r], sf[1][r]), fmaxf(sf[2][r], sf[3][r])) * 0.125f;
#pragma unroll
            for (int off = 1; off < 16; off <<= 1) mx = fmaxf(mx, __shfl_xor(mx, off));
            float mnew = fmaxf(mrow[r], mx);
            float alpha = __expf(mrow[r] - mnew);
            float rs = 0.f;
#pragma unroll
            for (int nt = 0; nt < 4; ++nt) {
                float p = __expf(sf[nt][r] * 0.125f - mnew);
                rs += p;
                Ps[w][quad * 4 + r][nt * 16 + ln] = f2b(p);
            }
#pragma unroll
            for (int off = 1; off < 16; off <<= 1) rs += __shfl_xor(rs, off);
            lrow[r] = lrow[r] * alpha + rs;
            mrow[r] = mnew;
#pragma unroll
            for (int nt = 0; nt < 4; ++nt) o[nt][r] *= alpha;
        }
        __syncthreads();   // Ps visible

        // O += P @ V  (A-frag from Ps, B-frag from Vs, both contiguous-K b128)
#pragma unroll
        for (int kc = 0; kc < 2; ++kc) {
            short8 pa = *(const short8*)(&Ps[w][ln][kc * 32 + quad * 8]);
#pragma unroll
            for (int nt = 0; nt < 4; ++nt) {
                short8 vb = *(const short8*)(&Vs[nt * 16 + ln][kc * 32 + quad * 8]);
                o[nt] = __builtin_amdgcn_mfma_f32_16x16x32_bf16(pa, vb, o[nt], 0, 0, 0);
            }
        }
    }
    // epilogue: normalize and write Ob[b*s][h*64+d] (bf16)
    const int b = bh >> 2, h = bh & 3;
#pragma unroll
    for (int r = 0; r < 4; ++r) {
        float inv = 1.0f / lrow[r];
        long row = (long)(b * SEQQ + q0 + w * 16 + quad * 4 + r);
#pragma unroll
        for (int nt = 0; nt < 4; ++nt)
            Ob[row * 256 + h * 64 + nt * 16 + ln] = f2b(o[nt][r] * inv);
    }
}

// ---------------------------------------------------------------------------
extern "C" void kernel_launch(void* const* d_in, const int* in_sizes, int n_in,
                              void* d_out, int out_size, void* d_ws, size_t ws_size,
                              hipStream_t stream) {
    const float* q   = (const float*)d_in[0];           // [4,2048,1024] f32
    const int*   qc  = (const int*)d_in[1];             // [4,2048,2] i32
    const float* kv  = (const float*)d_in[2];           // [4,2048,1024] f32
    const int*   kvc = (const int*)d_in[3];             // [4,2048,2] i32
    const float* Wq  = (const float*)d_in[4];           // [1024,16,64] f32
    const float* Wk  = (const float*)d_in[5];           // [1024,4,64] f32
    const float* Wv  = (const float*)d_in[6];           // [1024,4,64] f32
    const float* Wo  = (const float*)d_in[7];           // [256,1024] f32
    float* out = (float*)d_out;                         // [4,2048,1024] f32

    char* ws = (char*)d_ws;
    const size_t MB = 1024 * 1024;
    short* Wq_t  = (short*)(ws);                        // 0.5 MB [256][1024]
    short* Wkv_t = (short*)(ws + MB / 2);               // 1.0 MB [512][1024]
    short* Wo_t  = (short*)(ws + MB / 2 + MB);          // 0.5 MB [1024][256]
    float* Qp    = (float*)(ws + 2 * MB);               // 8 MB  [8192][256]
    float* KVp   = (float*)(ws + 10 * MB);              // 16 MB [8192][512]
    short* Qr    = (short*)(ws + 26 * MB);              // 4 MB  [16][2048][64]
    short* Kr    = (short*)(ws + 30 * MB);              // 4 MB
    short* Vr    = (short*)(ws + 34 * MB);              // 4 MB
    short* Ob    = (short*)(ws + 38 * MB);              // 4 MB  [8192][256]

    hipLaunchKernelGGL(prep_weights, dim3(4096), dim3(256), 0, stream,
                       Wq, Wk, Wv, Wo, Wq_t, Wkv_t, Wo_t);
    hipLaunchKernelGGL((gemm_bt<true>), dim3(128, 4), dim3(256), 0, stream,
                       (const void*)q, Wq_t, Qp, 8192, 256, 1024);
    hipLaunchKernelGGL((gemm_bt<true>), dim3(128, 8), dim3(256), 0, stream,
                       (const void*)kv, Wkv_t, KVp, 8192, 512, 1024);
    hipLaunchKernelGGL(rope_q_kernel, dim3(4096), dim3(256), 0, stream, Qp, qc, Qr);
    hipLaunchKernelGGL(rope_kv_kernel, dim3(4096), dim3(256), 0, stream, KVp, kvc, Kr, Vr);
    hipLaunchKernelGGL(attn_kernel, dim3(32, 16), dim3(256), 0, stream, Qr, Kr, Vr, Ob);
    hipLaunchKernelGGL((gemm_bt<false>), dim3(128, 16), dim3(256), 0, stream,
                       (const void*)Ob, Wo_t, out, 8192, 1024, 256);
}

// Round 3
// 291.595 us; speedup vs baseline: 1.3933x; 1.3933x over previous
//
#include <hip/hip_runtime.h>

#define BATCH 4
#define SEQQ  2048
#define SEQKV 2048
#define NH    4      // kv heads (effective q heads after group-sum over g)
#define HD    64
#define IND   1024
// 0.125 (1/sqrt(64)) * log2(e): folded into Qr so softmax runs in exp2 domain
#define QSCL 0.18033688011112042f

typedef __attribute__((ext_vector_type(8))) short short8;   // 8 x bf16 raw bits
typedef __attribute__((ext_vector_type(4))) float floatx4;  // MFMA accum

#if __has_builtin(__builtin_amdgcn_exp2f)
#define EXP2(x) __builtin_amdgcn_exp2f(x)
#else
#define EXP2(x) exp2f(x)
#endif

__device__ __forceinline__ short f2b(float f) {             // RNE
    unsigned u; __builtin_memcpy(&u, &f, 4);
    u = (u + 0x7fffu + ((u >> 16) & 1u)) >> 16;
    return (short)u;
}
__device__ __forceinline__ short8 cvt8(const float* p) {
    float4 a = *(const float4*)p;
    float4 b = *(const float4*)(p + 4);
    short8 r;
    r[0] = f2b(a.x); r[1] = f2b(a.y); r[2] = f2b(a.z); r[3] = f2b(a.w);
    r[4] = f2b(b.x); r[5] = f2b(b.y); r[6] = f2b(b.z); r[7] = f2b(b.w);
    return r;
}

// ---------------------------------------------------------------------------
// prep_all: weights (group-sum Wq + transpose to B^T bf16) + q/kv fp32->bf16.
// Grid 12288 x 256.
__global__ __launch_bounds__(256) void prep_all(
    const float* __restrict__ Wq, const float* __restrict__ Wk,
    const float* __restrict__ Wv, const float* __restrict__ Wo,
    const float* __restrict__ q, const float* __restrict__ kv,
    short* __restrict__ Wq_t, short* __restrict__ Wkv_t, short* __restrict__ Wo_t,
    short* __restrict__ qb, short* __restrict__ kvb) {
    int blk = blockIdx.x;
    if (blk < 4096) {
        int idx = blk * 256 + threadIdx.x;       // 1,048,576 total
        if (idx < 256 * 1024) {                  // Wq_t [256 n][1024 k]
            int n = idx >> 10, i = idx & 1023;
            int h = n >> 6, d = n & 63;
            float s = 0.f;
#pragma unroll
            for (int g = 0; g < 4; ++g) s += Wq[i * 1024 + (h * 4 + g) * 64 + d];
            Wq_t[idx] = f2b(s);
        } else if (idx < 768 * 1024) {           // Wkv_t [512 n][1024 k]
            int t = idx - 256 * 1024;
            int n = t >> 10, i = t & 1023;
            Wkv_t[t] = f2b((n < 256) ? Wk[i * 256 + n] : Wv[i * 256 + (n - 256)]);
        } else {                                 // Wo_t [1024 n][256 k]
            int t = idx - 768 * 1024;
            int n = t >> 8, k = t & 255;
            Wo_t[t] = f2b(Wo[k * 1024 + n]);
        }
    } else if (blk < 8192) {                     // q -> qb bf16
        long e = ((long)(blk - 4096) * 256 + threadIdx.x) * 8;
        *(short8*)(qb + e) = cvt8(q + e);
    } else {                                     // kv -> kvb bf16
        long e = ((long)(blk - 8192) * 256 + threadIdx.x) * 8;
        *(short8*)(kvb + e) = cvt8(kv + e);
    }
}

// ---------------------------------------------------------------------------
// m97-style GEMM body: C[M][N] f32 = A[M][K] bf16 row-major x Wt[N][K] bf16 (B^T).
// 128x128 tile, BK=32, block 256 = 4 waves in 2x2 quadrants of 64x64.
// global_load_lds width-16 staging, 2-barrier K-loop.
__device__ __forceinline__ void gemm128_body(
    const short* __restrict__ A, const short* __restrict__ Wt, float* __restrict__ C,
    int m0, int n0, int N, int K, short* As, short* Bs) {
    const int t = threadIdx.x;
    const int w = t >> 6, lane = t & 63, ln = lane & 15, quad = lane >> 4;
    const int wm = w >> 1, wn = w & 1;
    const int srow = lane >> 2, skc = (lane & 3) * 8;    // staging: 16 rows/issue, 4 lanes/row
    floatx4 acc[4][4];
#pragma unroll
    for (int mt = 0; mt < 4; ++mt)
#pragma unroll
        for (int nt = 0; nt < 4; ++nt) acc[mt][nt] = floatx4{0.f, 0.f, 0.f, 0.f};

    for (int ks = 0; ks < K; ks += 32) {
        __syncthreads();                                 // prev tile reads done
#pragma unroll
        for (int i = 0; i < 2; ++i) {
            __builtin_amdgcn_global_load_lds(
                (const void*)(A + (long)(m0 + w * 32 + i * 16 + srow) * K + ks + skc),
                (void*)(As + (w * 2 + i) * 512), 16, 0, 0);
            __builtin_amdgcn_global_load_lds(
                (const void*)(Wt + (long)(n0 + w * 32 + i * 16 + srow) * K + ks + skc),
                (void*)(Bs + (w * 2 + i) * 512), 16, 0, 0);
        }
        __syncthreads();                                 // staged (vmcnt drained at barrier)
        short8 af[4], bf[4];
#pragma unroll
        for (int mt = 0; mt < 4; ++mt)
            af[mt] = *(const short8*)(As + (wm * 64 + mt * 16 + ln) * 32 + quad * 8);
#pragma unroll
        for (int nt = 0; nt < 4; ++nt)
            bf[nt] = *(const short8*)(Bs + (wn * 64 + nt * 16 + ln) * 32 + quad * 8);
#pragma unroll
        for (int mt = 0; mt < 4; ++mt)
#pragma unroll
            for (int nt = 0; nt < 4; ++nt)
                acc[mt][nt] = __builtin_amdgcn_mfma_f32_16x16x32_bf16(af[mt], bf[nt], acc[mt][nt], 0, 0, 0);
    }
#pragma unroll
    for (int mt = 0; mt < 4; ++mt) {
        int row0 = m0 + wm * 64 + mt * 16 + quad * 4;
#pragma unroll
        for (int nt = 0; nt < 4; ++nt) {
            int col = n0 + wn * 64 + nt * 16 + ln;
#pragma unroll
            for (int r = 0; r < 4; ++r)
                C[(long)(row0 + r) * N + col] = acc[mt][nt][r];
        }
    }
}

// Fused Q+KV projection: blocks 0..127 -> Qp (N=256), 128..383 -> KVp (N=512).
__global__ __launch_bounds__(256) void proj_gemm(
    const short* __restrict__ qb, const short* __restrict__ kvb,
    const short* __restrict__ Wq_t, const short* __restrict__ Wkv_t,
    float* __restrict__ Qp, float* __restrict__ KVp) {
    __shared__ __align__(16) short As[128 * 32];
    __shared__ __align__(16) short Bs[128 * 32];
    int id = blockIdx.x;
    if (id < 128)
        gemm128_body(qb, Wq_t, Qp, (id >> 1) * 128, (id & 1) * 128, 256, 1024, As, Bs);
    else {
        int t = id - 128;
        gemm128_body(kvb, Wkv_t, KVp, (t >> 2) * 128, (t & 3) * 128, 512, 1024, As, Bs);
    }
}

// Final projection: Ob[8192][256] x Wo_t[1024][256] -> out[8192][1024].
__global__ __launch_bounds__(256) void final_gemm(
    const short* __restrict__ Ob, const short* __restrict__ Wo_t, float* __restrict__ out) {
    __shared__ __align__(16) short As[128 * 32];
    __shared__ __align__(16) short Bs[128 * 32];
    gemm128_body(Ob, Wo_t, out, blockIdx.x * 128, blockIdx.y * 128, 1024, 256, As, Bs);
}

// ---------------------------------------------------------------------------
// rope_all: blocks 0..4095 rope-Q (with QSCL fold), 4096..8191 rope-K,
// 8192..8703 V transpose (KVp V-half -> Vt[bh][64 d][2048 kv] bf16).
__global__ __launch_bounds__(256) void rope_all(
    const float* __restrict__ Qp, const int* __restrict__ qc,
    const float* __restrict__ KVp, const int* __restrict__ kvc,
    short* __restrict__ Qr, short* __restrict__ Kr, short* __restrict__ Vt) {
    __shared__ __align__(16) short Ts[64][72];
    int blk = blockIdx.x;
    if (blk < 8192) {
        bool isq = blk < 4096;
        int idx = (isq ? blk : blk - 4096) * 256 + threadIdx.x;
        int j = idx & 31, h = (idx >> 5) & 3, s = (idx >> 7) & 2047, b = idx >> 18;
        int bs = b * 2048 + s;
        const float* src = isq ? (Qp + (long)bs * 256) : (KVp + (long)bs * 512);
        float2 x = *(const float2*)(src + h * 64 + 2 * j);
        float c = (float)(isq ? qc : kvc)[bs * 2 + (j >> 4)];
        float ang = c * __expf((float)(j & 15) * -0.5756462732485114f); // -ln(1e4)/16
        float sn, cs; __sincosf(ang, &sn, &cs);
        if (isq) { sn *= QSCL; cs *= QSCL; }
        short2 o; o.x = f2b(x.x * cs - x.y * sn); o.y = f2b(x.x * sn + x.y * cs);
        short* dst = isq ? Qr : Kr;
        *(short2*)(dst + (long)((b * 4 + h) * 2048 + s) * 64 + 2 * j) = o;
    } else {
        int t2 = blk - 8192;                       // 512 blocks: (bh, kv-tile 64)
        int bh = t2 & 15, kt = (t2 >> 4) << 6;
        int b = bh >> 2, h = bh & 3;
        {   // load 64 kv-rows x 64 d fp32, scatter transposed into LDS
            int r = threadIdx.x >> 2, c = (threadIdx.x & 3) << 4;
            const float* src = KVp + (long)(b * 2048 + kt + r) * 512 + 256 + h * 64 + c;
#pragma unroll
            for (int j = 0; j < 16; ++j) Ts[c + j][r] = f2b(src[j]);
        }
        __syncthreads();
        {   // write coalesced along kv
            int d = threadIdx.x >> 2, c = (threadIdx.x & 3) << 4;
            long dst = ((long)bh * 64 + d) * 2048 + kt + c;
            *(short8*)(Vt + dst)     = *(const short8*)(&Ts[d][c]);
            *(short8*)(Vt + dst + 8) = *(const short8*)(&Ts[d][c + 8]);
        }
    }
}

// ---------------------------------------------------------------------------
// Flash attention, barrier-free. Grid 512 x 256 (4 waves x 16 q-rows).
// Qr (pre-scaled by QSCL), Kr [bh][s][64], Vt [bh][d][2048]. Out Ob[b*s][256] bf16.
// Per kv-tile(64): S via MFMA (K-frags double-buffered in regs), exp2-domain
// online softmax, P through per-wave LDS (stride 68, conflict-free), PV via
// MFMA with direct-global Vt B-frags; l via ones-column MFMA.
__global__ __launch_bounds__(256) void attn_kernel(
    const short* __restrict__ Qr, const short* __restrict__ Kr,
    const short* __restrict__ Vt, short* __restrict__ Ob) {
    __shared__ __align__(16) short Ps[4][16][68];
    const int id = blockIdx.x;
    const int bh = ((id & 7) << 1) | ((id >> 3) & 1);   // cluster 2 bh per XCD
    const int q0 = (id >> 4) * 64;
    const int w = threadIdx.x >> 6, lane = threadIdx.x & 63;
    const int ln = lane & 15, quad = lane >> 4;
    const short* Kb = Kr + (long)bh * SEQKV * HD;
    const short* Vb = Vt + (long)bh * HD * SEQKV;

    short8 qf[2];
    {
        const short* qp = Qr + (long)bh * SEQKV * HD + (long)(q0 + w * 16 + ln) * HD + quad * 8;
        qf[0] = *(const short8*)qp;
        qf[1] = *(const short8*)(qp + 32);
    }
    short8 ones;
#pragma unroll
    for (int j = 0; j < 8; ++j) ones[j] = (short)0x3F80;   // bf16 1.0

    floatx4 o[4], ol = {0.f, 0.f, 0.f, 0.f};
#pragma unroll
    for (int nt = 0; nt < 4; ++nt) o[nt] = floatx4{0.f, 0.f, 0.f, 0.f};
    float mrow[4] = {-1e30f, -1e30f, -1e30f, -1e30f};

    short8 kfA[4][2], kfB[4][2];
#pragma unroll
    for (int nt = 0; nt < 4; ++nt)
#pragma unroll
        for (int kc = 0; kc < 2; ++kc)
            kfA[nt][kc] = *(const short8*)(Kb + (long)(nt * 16 + ln) * HD + kc * 32 + quad * 8);

    auto body = [&](short8 (&kf)[4][2], short8 (&kfn)[4][2], int kt) {
        // S = Q K^T (exp2-domain scores; scale folded into Qr)
        floatx4 sf[4];
#pragma unroll
        for (int nt = 0; nt < 4; ++nt) {
            floatx4 z = {0.f, 0.f, 0.f, 0.f};
            z = __builtin_amdgcn_mfma_f32_16x16x32_bf16(qf[0], kf[nt][0], z, 0, 0, 0);
            sf[nt] = __builtin_amdgcn_mfma_f32_16x16x32_bf16(qf[1], kf[nt][1], z, 0, 0, 0);
        }
        // V frags (current tile) — latency hidden by softmax below
        short8 vf[4][2];
#pragma unroll
        for (int nt = 0; nt < 4; ++nt)
#pragma unroll
            for (int kc = 0; kc < 2; ++kc)
                vf[nt][kc] = *(const short8*)(Vb + (long)(nt * 16 + ln) * SEQKV + kt + kc * 32 + quad * 8);
        // K frags (next tile) — wraps harmlessly on last iter
        int ktn = (kt + 64) & (SEQKV - 1);
#pragma unroll
        for (int nt = 0; nt < 4; ++nt)
#pragma unroll
            for (int kc = 0; kc < 2; ++kc)
                kfn[nt][kc] = *(const short8*)(Kb + (long)(ktn + nt * 16 + ln) * HD + kc * 32 + quad * 8);
        // online softmax (rows quad*4+r live in this quad's 16 lanes)
        float alpha[4];
#pragma unroll
        for (int r = 0; r < 4; ++r) {
            float mx = fmaxf(fmaxf(sf[0][r], sf[1][r]), fmaxf(sf[2][r], sf[3][r]));
#pragma unroll
            for (int off = 1; off < 16; off <<= 1) mx = fmaxf(mx, __shfl_xor(mx, off, 16));
            float mnew = fmaxf(mrow[r], mx);
            alpha[r] = EXP2(mrow[r] - mnew);
            mrow[r] = mnew;
#pragma unroll
            for (int nt = 0; nt < 4; ++nt) {
                float p = EXP2(sf[nt][r] - mnew);
                unsigned pu; __builtin_memcpy(&pu, &p, 4);
                Ps[w][quad * 4 + r][nt * 16 + ln] = (short)((pu + 0x8000u) >> 16);
            }
        }
#pragma unroll
        for (int r = 0; r < 4; ++r) {
            ol[r] *= alpha[r];
#pragma unroll
            for (int nt = 0; nt < 4; ++nt) o[nt][r] *= alpha[r];
        }
        // O += P V ; l += P·1 (per-wave LDS round-trip, in-order DS, no barrier)
#pragma unroll
        for (int kc = 0; kc < 2; ++kc) {
            short8 pa = *(const short8*)(&Ps[w][ln][kc * 32 + quad * 8]);
#pragma unroll
            for (int nt = 0; nt < 4; ++nt)
                o[nt] = __builtin_amdgcn_mfma_f32_16x16x32_bf16(pa, vf[nt][kc], o[nt], 0, 0, 0);
            ol = __builtin_amdgcn_mfma_f32_16x16x32_bf16(pa, ones, ol, 0, 0, 0);
        }
    };

    for (int kt = 0; kt < SEQKV; kt += 128) {   // 2x unrolled: zero-copy K dbuf
        body(kfA, kfB, kt);
        body(kfB, kfA, kt + 64);
    }

    const int b = bh >> 2, h = bh & 3;
#pragma unroll
    for (int r = 0; r < 4; ++r) {
        float inv = 1.0f / ol[r];
        long row = (long)(b * SEQQ + q0 + w * 16 + quad * 4 + r);
#pragma unroll
        for (int nt = 0; nt < 4; ++nt)
            Ob[row * 256 + h * 64 + nt * 16 + ln] = f2b(o[nt][r] * inv);
    }
}

// ---------------------------------------------------------------------------
extern "C" void kernel_launch(void* const* d_in, const int* in_sizes, int n_in,
                              void* d_out, int out_size, void* d_ws, size_t ws_size,
                              hipStream_t stream) {
    const float* q   = (const float*)d_in[0];
    const int*   qc  = (const int*)d_in[1];
    const float* kv  = (const float*)d_in[2];
    const int*   kvc = (const int*)d_in[3];
    const float* Wq  = (const float*)d_in[4];
    const float* Wk  = (const float*)d_in[5];
    const float* Wv  = (const float*)d_in[6];
    const float* Wo  = (const float*)d_in[7];
    float* out = (float*)d_out;

    char* ws = (char*)d_ws;
    const size_t MB = 1024 * 1024;
    short* Wq_t  = (short*)(ws);                 // 0.5 MB  [256][1024]
    short* Wkv_t = (short*)(ws + MB / 2);        // 1.0 MB  [512][1024]
    short* Wo_t  = (short*)(ws + 3 * MB / 2);    // 0.5 MB  [1024][256]
    short* qb    = (short*)(ws + 2 * MB);        // 16 MB   [8192][1024] bf16
    short* kvb   = (short*)(ws + 18 * MB);       // 16 MB
    float* Qp    = (float*)(ws + 34 * MB);       // 8 MB    [8192][256]
    float* KVp   = (float*)(ws + 42 * MB);       // 16 MB   [8192][512]
    // overlays on qb (dead after proj_gemm):
    short* Qr    = (short*)(ws + 2 * MB);        // 4 MB  [16][2048][64]
    short* Kr    = (short*)(ws + 6 * MB);        // 4 MB
    short* Vt    = (short*)(ws + 10 * MB);       // 4 MB  [16][64][2048]
    short* Ob    = (short*)(ws + 14 * MB);       // 4 MB  [8192][256]

    hipLaunchKernelGGL(prep_all, dim3(12288), dim3(256), 0, stream,
                       Wq, Wk, Wv, Wo, q, kv, Wq_t, Wkv_t, Wo_t, qb, kvb);
    hipLaunchKernelGGL(proj_gemm, dim3(384), dim3(256), 0, stream,
                       qb, kvb, Wq_t, Wkv_t, Qp, KVp);
    hipLaunchKernelGGL(rope_all, dim3(8704), dim3(256), 0, stream,
                       Qp, qc, KVp, kvc, Qr, Kr, Vt);
    hipLaunchKernelGGL(attn_kernel, dim3(512), dim3(256), 0, stream, Qr, Kr, Vt, Ob);
    hipLaunchKernelGGL(final_gemm, dim3(64, 8), dim3(256), 0, stream, Ob, Wo_t, out);
}